// Round 3
// baseline (8460.652 us; speedup 1.0000x reference)
//
#include <hip/hip_runtime.h>

// ============================================================================
// 2-layer dynamic-quantized LSTM, T=1024, B=16, I=H=1024.  Round 3.
//
//  - Persistent kernel, 64 blocks x 512 threads (32 blocks/layer, 8 waves).
//  - Packed publication: per block per step ONE coherent dwordx2
//    {flag = step+1, bits = absmax of its h chunk} in a 2-slot ring.
//    Readers poll 32 of these with one lane-parallel load; the SAME load
//    delivers all block-maxes -> shfl_xor reduce = global absmax. No atomic
//    RMW, no separate hmax read. All 8 waves poll (no barrier to release).
//  - Gate-interleaved columns: lane = [grp:2][gate:2][unit:2]; each wave owns
//    4 hidden units x 4 gates. LSTM cell gathered with 4 __shfl in-wave.
//    No gl/hstash LDS, 2 syncthreads/step total.
//  - Layer0 x-operand (static int8 xq) loaded directly into A-fragments
//    before the poll (overlaps flag latency). h-operand staged via LDS.
//  - Layer decoupling as round 2: h0q int8 8-slot ring (producer-quantized
//    one step late), hmax0f scalar per t, flags0>=u+2 handshake, ring guard
//    flags1>=s-8.
//
// Workspace:
//   [0,16)      u32 wmax[4]
//   [128,640)   v2u pubs0[2][32]   [640,1152) v2u pubs1[2][32]
//   [4096,8192) u32 hmax0f[1024]
//   [8192,12K)  f32 xscale[1024]
//   [64K,192K)  f32 h0f[2][16384]  [192K,320K) f32 h1f[2][16384]
//   [320K,448K) i8  h0q[8][16384]
//   [1M,17M)    i8  wq[4][4096][1024]
//   [17M,33M)   i8  xq[1024][16][1024]
// ============================================================================

#define T_STEPS 1024

typedef int v4i __attribute__((ext_vector_type(4)));
typedef float v4f __attribute__((ext_vector_type(4)));
typedef unsigned v2u __attribute__((ext_vector_type(2)));

#define DEV static __device__ __forceinline__

DEV float qclip(float v) { return fminf(fmaxf(v, -127.0f), 127.0f); }

DEV unsigned pack4i(float a, float b, float c, float d) {
  int ia = (int)a, ib = (int)b, ic = (int)c, id = (int)d;
  return (unsigned)(ia & 0xff) | ((unsigned)(ib & 0xff) << 8) |
         ((unsigned)(ic & 0xff) << 16) | ((unsigned)(id & 0xff) << 24);
}

DEV float qdiv(float v, float s) { return qclip(rintf(v / s)); }      // one-time
DEV float qmul(float v, float inv) { return qclip(rintf(v * inv)); }  // hot loop

// ---- coherent (LLC) memory ops: bypass non-coherent L1/L2 ------------------
DEV v4i cloadi(const void* p) {
  v4i r;
  asm volatile("global_load_dwordx4 %0, %1, off sc0 sc1" : "=v"(r) : "v"(p) : "memory");
  return r;
}
DEV v4f cloadf(const void* p) {
  v4f r;
  asm volatile("global_load_dwordx4 %0, %1, off sc0 sc1" : "=v"(r) : "v"(p) : "memory");
  return r;
}
DEV unsigned cload4(const void* p) {
  unsigned r;
  asm volatile("global_load_dword %0, %1, off sc0 sc1" : "=v"(r) : "v"(p) : "memory");
  return r;
}
DEV v2u cload8w(const void* p) {  // poll load: wait included
  v2u r;
  asm volatile("global_load_dwordx2 %0, %1, off sc0 sc1\n\ts_waitcnt vmcnt(0)"
               : "=v"(r) : "v"(p) : "memory");
  return r;
}
DEV void cstore16(void* p, v4f v) {
  asm volatile("global_store_dwordx4 %0, %1, off sc0 sc1" :: "v"(p), "v"(v) : "memory");
}
DEV void cstore8(void* p, v2u v) {
  asm volatile("global_store_dwordx2 %0, %1, off sc0 sc1" :: "v"(p), "v"(v) : "memory");
}
DEV void cstore4f(void* p, float v) {
  asm volatile("global_store_dword %0, %1, off sc0 sc1" :: "v"(p), "v"(v) : "memory");
}
DEV void cstoreb(void* p, unsigned v) {
  asm volatile("global_store_byte %0, %1, off sc0 sc1" :: "v"(p), "v"(v) : "memory");
}
DEV void vdone() {  // drain this wave's vmem; fence scheduler (rule 18)
  asm volatile("s_waitcnt vmcnt(0)" ::: "memory");
  __builtin_amdgcn_sched_barrier(0);
}

#define MFMA_I8 __builtin_amdgcn_mfma_i32_16x16x64_i8

// ---------------------------------------------------------------------------
__global__ void init_kernel(const float* __restrict__ h0in, char* __restrict__ ws) {
  const int layer = blockIdx.x;
  const int tid = threadIdx.x;
  const float* src = h0in + layer * 16384;
  float* ring = (float*)(ws + (layer ? 196608 : 65536)) + 16384;  // slot 1
  v2u* pubs = (v2u*)(ws + (layer ? 640 : 128)) + 32;              // slot 1
  for (int i = tid; i < 4096; i += 256) {
    v4f v = ((const v4f*)src)[i];
    cstore16((char*)ring + ((size_t)i << 4), v);
  }
  __shared__ float red[256];
  const int lb = tid >> 3, su = tid & 7;
  float m = 0.0f;
  for (int b = su * 2; b < su * 2 + 2; ++b)
    for (int q = 0; q < 32; ++q) m = fmaxf(m, fabsf(src[b * 1024 + lb * 32 + q]));
  red[tid] = m;
  __syncthreads();
  if (su == 0) {
    float mm = red[tid];
#pragma unroll
    for (int i = 1; i < 8; ++i) mm = fmaxf(mm, red[tid + i]);
    v2u p;
    p.x = 0u;
    p.y = __float_as_uint(mm);
    cstore8((char*)&pubs[lb], p);
  }
}

// ---------------------------------------------------------------------------
__global__ void wabsmax_kernel(const float* __restrict__ w0, const float* __restrict__ w1,
                               const float* __restrict__ w2, const float* __restrict__ w3,
                               unsigned* wmax) {
  const int tensor = blockIdx.x >> 8;
  const int blk = blockIdx.x & 255;
  const float* w = tensor == 0 ? w0 : tensor == 1 ? w1 : tensor == 2 ? w2 : w3;
  const int tid = threadIdx.x;
  const float4* src = (const float4*)w;
  float m = 0.0f;
#pragma unroll
  for (int i = 0; i < 16; ++i) {
    float4 v = src[blk * 4096 + (i << 8) + tid];
    m = fmaxf(m, fmaxf(fmaxf(fabsf(v.x), fabsf(v.y)), fmaxf(fabsf(v.z), fabsf(v.w))));
  }
  __shared__ float red[256];
  red[tid] = m;
  __syncthreads();
  for (int off = 128; off > 0; off >>= 1) {
    if (tid < off) red[tid] = fmaxf(red[tid], red[tid + off]);
    __syncthreads();
  }
  if (tid == 0)
    __hip_atomic_fetch_max(&wmax[tensor], __float_as_uint(red[0]),
                           __ATOMIC_RELAXED, __HIP_MEMORY_SCOPE_AGENT);
}

// ---------------------------------------------------------------------------
__global__ void wquant_kernel(const float* __restrict__ w0, const float* __restrict__ w1,
                              const float* __restrict__ w2, const float* __restrict__ w3,
                              const unsigned* __restrict__ wmax,
                              unsigned char* __restrict__ wq) {
  const int tensor = blockIdx.x >> 12;
  const int blk = blockIdx.x & 4095;
  const float* w = tensor == 0 ? w0 : tensor == 1 ? w1 : tensor == 2 ? w2 : w3;
  const float s = fmaxf(__uint_as_float(wmax[tensor]), 1e-8f) / 127.0f;
  const int f4 = (blk << 8) + threadIdx.x;
  float4 v = ((const float4*)w)[f4];
  unsigned* dst = (unsigned*)(wq + (size_t)tensor * 4194304u);
  dst[f4] = pack4i(qdiv(v.x, s), qdiv(v.y, s), qdiv(v.z, s), qdiv(v.w, s));
}

// ---------------------------------------------------------------------------
__global__ void xquant_kernel(const float* __restrict__ x, float* __restrict__ xscale,
                              unsigned char* __restrict__ xq) {
  const int t = blockIdx.x;
  const int tid = threadIdx.x;
  const float4* src = (const float4*)(x + (size_t)t * 16384u);
  float4 vb[16];
  float m = 0.0f;
#pragma unroll
  for (int i = 0; i < 16; ++i) {
    float4 v = src[(i << 8) + tid];
    vb[i] = v;
    m = fmaxf(m, fmaxf(fmaxf(fabsf(v.x), fabsf(v.y)), fmaxf(fabsf(v.z), fabsf(v.w))));
  }
  __shared__ float red[256];
  red[tid] = m;
  __syncthreads();
  for (int off = 128; off > 0; off >>= 1) {
    if (tid < off) red[tid] = fmaxf(red[tid], red[tid + off]);
    __syncthreads();
  }
  __shared__ float ssh;
  if (tid == 0) {
    float s = fmaxf(red[0], 1e-8f) / 127.0f;
    xscale[t] = s;
    ssh = s;
  }
  __syncthreads();
  const float s = ssh;
  unsigned* dst = (unsigned*)(xq + (size_t)t * 16384u);
#pragma unroll
  for (int i = 0; i < 16; ++i) {
    float4 v = vb[i];
    dst[(i << 8) + tid] = pack4i(qdiv(v.x, s), qdiv(v.y, s), qdiv(v.z, s), qdiv(v.w, s));
  }
}

// ---------------------------------------------------------------------------
__global__ __launch_bounds__(512, 2) void seq_kernel(
    const unsigned char* __restrict__ xq, const float* __restrict__ xscale,
    const unsigned char* __restrict__ wq_base, const unsigned* __restrict__ wmax,
    const float* __restrict__ bih0, const float* __restrict__ bhh0,
    const float* __restrict__ bih1, const float* __restrict__ bhh1,
    char* __restrict__ ws, const float* __restrict__ c0in, float* __restrict__ dout) {
  const int blk = blockIdx.x;
  const int layer = blk >> 5;
  const int lb = blk & 31;
  const int j0 = lb << 5;
  const int tid = threadIdx.x;
  const int w = tid >> 6;
  const int lane = tid & 63;
  const int gate = (lane >> 2) & 3;       // lane bits 2-3
  const int unit = j0 + (w << 2) + (lane & 3);
  const int b0 = (lane >> 4) << 2;        // batches b0..b0+3 (D rows)

  v2u* pubs0 = (v2u*)(ws + 128);
  v2u* pubs1 = (v2u*)(ws + 640);
  unsigned* hmax0f = (unsigned*)(ws + 4096);
  float* h0f = (float*)(ws + 65536);
  float* h1f = (float*)(ws + 196608);
  unsigned char* h0qp = (unsigned char*)(ws + 327680);

  __shared__ __align__(16) unsigned char ahq[16][1040];
  __shared__ __align__(16) unsigned char axq[16][1040];
  __shared__ float redw[8];

  const unsigned char* wqi = wq_base + (size_t)(2 * layer) * 4194304u;
  const unsigned char* wqh = wq_base + (size_t)(2 * layer + 1) * 4194304u;
  const float s_wi = fmaxf(__uint_as_float(wmax[2 * layer + 0]), 1e-8f) / 127.0f;
  const float s_wh = fmaxf(__uint_as_float(wmax[2 * layer + 1]), 1e-8f) / 127.0f;

  // MFMA 16x16x64 i8 mapping: A row = lane&15, B col = lane&15,
  // k-group = lane>>4 (16 bytes each); D col = lane&15, row = (lane>>4)*4+r.
  const int ncol = (gate << 10) + unit;
  const int ksub = (lane >> 4) << 4;
  const int arow = lane & 15;

  v4i wfi[16], wfh[16];
  {
    const unsigned char* pi = wqi + (size_t)ncol * 1024u + ksub;
    const unsigned char* ph = wqh + (size_t)ncol * 1024u + ksub;
#pragma unroll
    for (int kk = 0; kk < 16; ++kk) {
      wfi[kk] = *(const v4i*)(pi + (kk << 6));
      wfh[kk] = *(const v4i*)(ph + (kk << 6));
    }
  }
  const float bsum = (layer ? bih1 : bih0)[ncol] + (layer ? bhh1 : bhh0)[ncol];

  float cr[4], hpv[4] = {0.f, 0.f, 0.f, 0.f};
#pragma unroll
  for (int r = 0; r < 4; ++r) cr[r] = c0in[(layer << 14) + ((b0 + r) << 10) + unit];

  const int gbase = lane & ~12;  // lane with gate bits cleared

  if (layer == 0) {
    // ========================= LAYER 0: s = 0..T ==========================
    for (int s = 0; s <= T_STEPS; ++s) {
      const bool full = (s < T_STEPS);
      v4i ax0 = {0, 0, 0, 0}, ax1 = {0, 0, 0, 0};
      float sxs = 0.f;
      if (full) {
        sxs = xscale[s];
        const unsigned char* xb = xq + ((size_t)s << 14) + (arow << 10) + ksub;
        v4i xa[8];
#pragma unroll
        for (int kk = 0; kk < 8; ++kk) xa[kk] = *(const v4i*)(xb + (kk << 6));
#pragma unroll
        for (int kk = 0; kk < 8; kk += 2) {
          ax0 = MFMA_I8(xa[kk], wfi[kk], ax0, 0, 0, 0);
          ax1 = MFMA_I8(xa[kk + 1], wfi[kk + 1], ax1, 0, 0, 0);
        }
#pragma unroll
        for (int kk = 0; kk < 8; ++kk) xa[kk] = *(const v4i*)(xb + ((kk + 8) << 6));
#pragma unroll
        for (int kk = 0; kk < 8; kk += 2) {
          ax0 = MFMA_I8(xa[kk], wfi[kk + 8], ax0, 0, 0, 0);
          ax1 = MFMA_I8(xa[kk + 1], wfi[kk + 9], ax1, 0, 0, 0);
        }
      }
      // ---- poll: lanes<32 own pubs (capture max of h0(s-1)); lanes>=32 ring guard
      const v2u* pp;
      unsigned tgt;
      if (lane < 32) {
        pp = pubs0 + (((s + 1) & 1) << 5) + lane;
        tgt = (unsigned)s;
      } else {
        int slot = (s >= 9) ? ((s - 9) & 1) : 0;
        pp = pubs1 + (slot << 5) + (lane - 32);
        tgt = (s >= 9) ? (unsigned)(s - 8) : 0u;
      }
      v2u pv;
      unsigned guard = 0;
      for (;;) {
        pv = cload8w(pp);
        if (__ballot(pv.x >= tgt) == ~0ull) break;
        __builtin_amdgcn_s_sleep(1);
        if (++guard > (1u << 20)) break;
      }
      float pm = __uint_as_float(pv.y);
#pragma unroll
      for (int m = 1; m < 32; m <<= 1) pm = fmaxf(pm, __shfl_xor(pm, m));
      const float gmax = __shfl(pm, 0);  // absmax of h0(s-1)
      const float sh = fmaxf(gmax, 1e-8f) / 127.0f;
      const float inv = 1.0f / sh;

      // issue own-h ring loads FIRST (critical path)
      v4f hv[8];
      if (full) {
        const char* hsrc = (const char*)(h0f + ((size_t)((s + 1) & 1) << 14));
#pragma unroll
        for (int i = 0; i < 8; ++i) hv[i] = cloadf(hsrc + ((size_t)(((i << 9) + tid)) << 4));
      }
      // publish h0q(s-1) + final max for layer1 (from registers)
      if (s > 0) {
        if (gate == 0) {
          unsigned char* qb = h0qp + ((size_t)((s - 1) & 7) << 14) + unit;
#pragma unroll
          for (int r = 0; r < 4; ++r) {
            int q = (int)qmul(hpv[r], inv);
            cstoreb(qb + ((b0 + r) << 10), (unsigned)(q & 0xff));
          }
        }
        if (lb == 0 && tid == 0) cstore4f((char*)&hmax0f[s - 1], gmax);
      }
      vdone();
      if (full) {
#pragma unroll
        for (int i = 0; i < 8; ++i) {
          unsigned u = pack4i(qmul(hv[i].x, inv), qmul(hv[i].y, inv),
                              qmul(hv[i].z, inv), qmul(hv[i].w, inv));
          int e = ((i << 9) + tid) << 2;
          *(unsigned*)&ahq[e >> 10][e & 1023] = u;
        }
        __syncthreads();
        v4i ah0 = {0, 0, 0, 0}, ah1 = {0, 0, 0, 0};
#pragma unroll
        for (int kk = 0; kk < 16; kk += 2) {
          v4i a = *(const v4i*)&ahq[arow][(kk << 6) + ksub];
          v4i b = *(const v4i*)&ahq[arow][((kk + 1) << 6) + ksub];
          ah0 = MFMA_I8(a, wfh[kk], ah0, 0, 0, 0);
          ah1 = MFMA_I8(b, wfh[kk + 1], ah1, 0, 0, 0);
        }
        const float fx = sxs * s_wi, fh = sh * s_wh;
        float am = 0.f;
#pragma unroll
        for (int r = 0; r < 4; ++r) {
          float gv = (float)(ax0[r] + ax1[r]) * fx + (float)(ah0[r] + ah1[r]) * fh + bsum;
          float xxv = (gate == 2) ? 2.f * gv : gv;
          float sg = 1.f / (1.f + expf(-xxv));
          float act = (gate == 2) ? 2.f * sg - 1.f : sg;
          float gi = __shfl(act, gbase);
          float gf = __shfl(act, gbase | 4);
          float gg = __shfl(act, gbase | 8);
          float go = __shfl(act, gbase | 12);
          float cn = gf * cr[r] + gi * gg;
          cr[r] = cn;
          float th = 2.f / (1.f + expf(-2.f * cn)) - 1.f;
          float h = go * th;
          hpv[r] = h;
          am = fmaxf(am, fabsf(h));
        }
        if (gate == 0) {
          char* hb = (char*)(h0f + ((size_t)(s & 1) << 14)) + (unit << 2);
#pragma unroll
          for (int r = 0; r < 4; ++r) cstore4f(hb + ((size_t)(b0 + r) << 12), hpv[r]);
          if (s == T_STEPS - 1) {
#pragma unroll
            for (int r = 0; r < 4; ++r) dout[16777216u + ((b0 + r) << 10) + unit] = hpv[r];
          }
        }
#pragma unroll
        for (int m = 1; m < 64; m <<= 1) am = fmaxf(am, __shfl_xor(am, m));
        if (lane == 0) redw[w] = am;
      }
      vdone();
      __syncthreads();
      if (tid == 0) {
        float bm = redw[0];
#pragma unroll
        for (int i = 1; i < 8; ++i) bm = fmaxf(bm, redw[i]);
        v2u pub;
        pub.x = (unsigned)(s + 1);
        pub.y = __float_as_uint(bm);
        cstore8((char*)(pubs0 + ((s & 1) << 5) + lb), pub);
      }
    }
    if (gate == 0) {
#pragma unroll
      for (int r = 0; r < 4; ++r)
        dout[16777216u + 32768u + ((b0 + r) << 10) + unit] = cr[r];
    }
  } else {
    // ========================= LAYER 1: u = 0..T-1 ========================
    for (int u = 0; u < T_STEPS; ++u) {
      // combined poll: lanes<32: flags0 >= u+2 ; lanes>=32: own pubs1 >= u (capture max)
      const v2u* pp;
      unsigned tgt;
      if (lane < 32) {
        pp = pubs0 + (((u + 1) & 1) << 5) + lane;
        tgt = (unsigned)(u + 2);
      } else {
        pp = pubs1 + (((u + 1) & 1) << 5) + (lane - 32);
        tgt = (unsigned)u;
      }
      v2u pv;
      unsigned guard = 0;
      for (;;) {
        pv = cload8w(pp);
        if (__ballot(pv.x >= tgt) == ~0ull) break;
        __builtin_amdgcn_s_sleep(1);
        if (++guard > (1u << 20)) break;
      }
      float pm = __uint_as_float(pv.y);
#pragma unroll
      for (int m = 1; m < 32; m <<= 1) pm = fmaxf(pm, __shfl_xor(pm, m));
      const float gmax1 = __shfl(pm, 32);  // absmax of h1(u-1)
      const float sh = fmaxf(gmax1, 1e-8f) / 127.0f;
      const float inv = 1.0f / sh;

      // issue all loads: x-side int8 h0q, own-h f32 ring, x scale
      const char* qsrc = (const char*)h0qp + ((size_t)(u & 7) << 14);
      v4i q0 = cloadi(qsrc + ((size_t)tid << 4));
      v4i q1 = cloadi(qsrc + 8192 + ((size_t)tid << 4));
      const char* hsrc = (const char*)(h1f + ((size_t)((u + 1) & 1) << 14));
      v4f hv[8];
#pragma unroll
      for (int i = 0; i < 8; ++i) hv[i] = cloadf(hsrc + ((size_t)(((i << 9) + tid)) << 4));
      unsigned sxb = cload4((const char*)&hmax0f[u]);
      vdone();
      const float sx = fmaxf(__uint_as_float(sxb), 1e-8f) / 127.0f;
      {
        int e0 = tid << 4;
        *(v4i*)&axq[e0 >> 10][e0 & 1023] = q0;
        int e1 = 8192 + (tid << 4);
        *(v4i*)&axq[e1 >> 10][e1 & 1023] = q1;
      }
#pragma unroll
      for (int i = 0; i < 8; ++i) {
        unsigned uq = pack4i(qmul(hv[i].x, inv), qmul(hv[i].y, inv),
                             qmul(hv[i].z, inv), qmul(hv[i].w, inv));
        int e = ((i << 9) + tid) << 2;
        *(unsigned*)&ahq[e >> 10][e & 1023] = uq;
      }
      __syncthreads();
      v4i ax0 = {0, 0, 0, 0}, ax1 = {0, 0, 0, 0};
      v4i ah0 = {0, 0, 0, 0}, ah1 = {0, 0, 0, 0};
#pragma unroll
      for (int kk = 0; kk < 16; kk += 2) {
        v4i a0 = *(const v4i*)&axq[arow][(kk << 6) + ksub];
        v4i a1 = *(const v4i*)&axq[arow][((kk + 1) << 6) + ksub];
        v4i b0v = *(const v4i*)&ahq[arow][(kk << 6) + ksub];
        v4i b1v = *(const v4i*)&ahq[arow][((kk + 1) << 6) + ksub];
        ax0 = MFMA_I8(a0, wfi[kk], ax0, 0, 0, 0);
        ax1 = MFMA_I8(a1, wfi[kk + 1], ax1, 0, 0, 0);
        ah0 = MFMA_I8(b0v, wfh[kk], ah0, 0, 0, 0);
        ah1 = MFMA_I8(b1v, wfh[kk + 1], ah1, 0, 0, 0);
      }
      const float fx = sx * s_wi, fh = sh * s_wh;
      float am = 0.f;
#pragma unroll
      for (int r = 0; r < 4; ++r) {
        float gv = (float)(ax0[r] + ax1[r]) * fx + (float)(ah0[r] + ah1[r]) * fh + bsum;
        float xxv = (gate == 2) ? 2.f * gv : gv;
        float sg = 1.f / (1.f + expf(-xxv));
        float act = (gate == 2) ? 2.f * sg - 1.f : sg;
        float gi = __shfl(act, gbase);
        float gf = __shfl(act, gbase | 4);
        float gg = __shfl(act, gbase | 8);
        float go = __shfl(act, gbase | 12);
        float cn = gf * cr[r] + gi * gg;
        cr[r] = cn;
        float th = 2.f / (1.f + expf(-2.f * cn)) - 1.f;
        float h = go * th;
        hpv[r] = h;
        am = fmaxf(am, fabsf(h));
      }
      if (gate == 0) {
        char* hb = (char*)(h1f + ((size_t)(u & 1) << 14)) + (unit << 2);
        float* yb = dout + ((size_t)u << 14) + unit;
#pragma unroll
        for (int r = 0; r < 4; ++r) {
          cstore4f(hb + ((size_t)(b0 + r) << 12), hpv[r]);
          yb[(size_t)(b0 + r) << 10] = hpv[r];
        }
        if (u == T_STEPS - 1) {
#pragma unroll
          for (int r = 0; r < 4; ++r)
            dout[16777216u + 16384u + ((b0 + r) << 10) + unit] = hpv[r];
        }
      }
#pragma unroll
      for (int m = 1; m < 64; m <<= 1) am = fmaxf(am, __shfl_xor(am, m));
      if (lane == 0) redw[w] = am;
      vdone();
      __syncthreads();
      if (tid == 0) {
        float bm = redw[0];
#pragma unroll
        for (int i = 1; i < 8; ++i) bm = fmaxf(bm, redw[i]);
        v2u pub;
        pub.x = (unsigned)(u + 1);
        pub.y = __float_as_uint(bm);
        cstore8((char*)(pubs1 + ((u & 1) << 5) + lb), pub);
      }
    }
    if (gate == 0) {
#pragma unroll
      for (int r = 0; r < 4; ++r)
        dout[16777216u + 32768u + 16384u + ((b0 + r) << 10) + unit] = cr[r];
    }
  }
}

// ---------------------------------------------------------------------------
extern "C" void kernel_launch(void* const* d_in, const int* in_sizes, int n_in,
                              void* d_out, int out_size, void* d_ws, size_t ws_size,
                              hipStream_t stream) {
  (void)in_sizes; (void)n_in; (void)out_size; (void)ws_size;
  const float* x     = (const float*)d_in[0];
  const float* h0in  = (const float*)d_in[1];
  const float* c0in  = (const float*)d_in[2];
  const float* w_ih0 = (const float*)d_in[3];
  const float* w_hh0 = (const float*)d_in[4];
  const float* b_ih0 = (const float*)d_in[5];
  const float* b_hh0 = (const float*)d_in[6];
  const float* w_ih1 = (const float*)d_in[7];
  const float* w_hh1 = (const float*)d_in[8];
  const float* b_ih1 = (const float*)d_in[9];
  const float* b_hh1 = (const float*)d_in[10];

  char* ws = (char*)d_ws;
  unsigned* wmax   = (unsigned*)(ws + 0);
  float* xscale    = (float*)(ws + 8192);
  unsigned char* wqb = (unsigned char*)(ws + (1u << 20));
  unsigned char* xq  = (unsigned char*)(ws + (1u << 20) + 4u * 4194304u);

  hipMemsetAsync(ws, 0, 65536, stream);  // wmax, pubs, hmax0f, xscale
  hipLaunchKernelGGL(init_kernel, dim3(2), dim3(256), 0, stream, h0in, ws);
  hipLaunchKernelGGL(wabsmax_kernel, dim3(1024), dim3(256), 0, stream,
                     w_ih0, w_hh0, w_ih1, w_hh1, wmax);
  hipLaunchKernelGGL(wquant_kernel, dim3(16384), dim3(256), 0, stream,
                     w_ih0, w_hh0, w_ih1, w_hh1, wmax, wqb);
  hipLaunchKernelGGL(xquant_kernel, dim3(1024), dim3(256), 0, stream,
                     x, xscale, xq);
  hipLaunchKernelGGL(seq_kernel, dim3(64), dim3(512), 0, stream,
                     xq, xscale, wqb, wmax,
                     b_ih0, b_hh0, b_ih1, b_hh1,
                     ws, c0in, (float*)d_out);
}

// Round 4
// 5758.975 us; speedup vs baseline: 1.4691x; 1.4691x over previous
//
#include <hip/hip_runtime.h>

// ============================================================================
// 2-layer dynamic-quantized LSTM, T=1024, B=16, I=H=1024.  Round 4.
//
// Structure = round 2 (coalesced packed publishes) + round-3 wins:
//  - 64 blocks x 512 threads (32 blocks/layer, 8 waves, 32 units/block),
//    int8 weights in VGPRs (128/wave) for all 1024 steps.
//  - ALL cross-block buffers packed by producer chunk (full-line coherent
//    stores): h rings [slot][lb][16][32] f32, h0q ring [slot8][lb][16][32] i8.
//  - Pub = ONE dwordx2 {flag, blockmax} per block per step; poll load
//    delivers all 32 maxes -> shfl_xor reduce. Uniform slot (step+1)&1.
//  - Critical path per step: poll -> issue 8 coherent h loads -> reduce ->
//    vmcnt(0) -> quant -> LDS -> barrier -> 16 MFMA -> shfl cell ->
//    packed publish -> flag. h0q/hmax publishes ride the MFMA phase.
//  - Layer0 x-side: xq stored SWIZZLED in fragment order; 16 coalesced
//    plain loads -> direct MFMA A-fragments, all pre-poll (dead time).
//  - Layer1 x-side = h0q(u) (packed int8, published from layer0's ahq LDS
//    during its step u+1); sx scale via hmax0f[u] loaded with the batch.
//
// Workspace (~33 MB):
//   [0,16)      u32 wmax[4]
//   [128,640)   v2u pubs0[2][32]   [640,1152) v2u pubs1[2][32]
//   [4096,8192) f32 hmax0f[1024]
//   [8192,12K)  f32 xscale[1024]
//   [64K,192K)  f32 h0f[2][32][16][32]   [192K,320K) f32 h1f[2][32][16][32]
//   [320K,448K) i8  h0q[8][32][16][32]
//   [1M,17M)    i8  wq[4][4096][1024]
//   [17M,33M)   i8  xq_sw[1024][16][64][16]   (fragment-swizzled)
// ============================================================================

#define T_STEPS 1024

typedef int v4i __attribute__((ext_vector_type(4)));
typedef float v4f __attribute__((ext_vector_type(4)));
typedef unsigned v2u __attribute__((ext_vector_type(2)));

#define DEV static __device__ __forceinline__

DEV float qclip(float v) { return fminf(fmaxf(v, -127.0f), 127.0f); }

DEV unsigned pack4i(float a, float b, float c, float d) {
  int ia = (int)a, ib = (int)b, ic = (int)c, id = (int)d;
  return (unsigned)(ia & 0xff) | ((unsigned)(ib & 0xff) << 8) |
         ((unsigned)(ic & 0xff) << 16) | ((unsigned)(id & 0xff) << 24);
}

DEV float qdiv(float v, float s) { return qclip(rintf(v / s)); }      // one-time
DEV float qmul(float v, float inv) { return qclip(rintf(v * inv)); }  // hot loop

// ---- coherent (LLC) ops: bypass non-coherent per-XCD L1/L2 -----------------
DEV v4i cloadi(const void* p) {
  v4i r;
  asm volatile("global_load_dwordx4 %0, %1, off sc0 sc1" : "=v"(r) : "v"(p) : "memory");
  return r;
}
DEV v4f cloadf(const void* p) {
  v4f r;
  asm volatile("global_load_dwordx4 %0, %1, off sc0 sc1" : "=v"(r) : "v"(p) : "memory");
  return r;
}
DEV unsigned cload4(const void* p) {
  unsigned r;
  asm volatile("global_load_dword %0, %1, off sc0 sc1" : "=v"(r) : "v"(p) : "memory");
  return r;
}
DEV v2u cload8w(const void* p) {  // poll load, wait included
  v2u r;
  asm volatile("global_load_dwordx2 %0, %1, off sc0 sc1\n\ts_waitcnt vmcnt(0)"
               : "=v"(r) : "v"(p) : "memory");
  return r;
}
DEV void cstore16(void* p, v4f v) {
  asm volatile("global_store_dwordx4 %0, %1, off sc0 sc1" :: "v"(p), "v"(v) : "memory");
}
DEV void cstore8(void* p, v2u v) {
  asm volatile("global_store_dwordx2 %0, %1, off sc0 sc1" :: "v"(p), "v"(v) : "memory");
}
DEV void cstore4u(void* p, unsigned v) {
  asm volatile("global_store_dword %0, %1, off sc0 sc1" :: "v"(p), "v"(v) : "memory");
}
DEV void cstore4f(void* p, float v) {
  asm volatile("global_store_dword %0, %1, off sc0 sc1" :: "v"(p), "v"(v) : "memory");
}
DEV void vdone() {  // drain this wave's vmem; fence scheduler (rule 18)
  asm volatile("s_waitcnt vmcnt(0)" ::: "memory");
  __builtin_amdgcn_sched_barrier(0);
}

#define MFMA_I8 __builtin_amdgcn_mfma_i32_16x16x64_i8

// ---------------------------------------------------------------------------
__global__ void init_kernel(const float* __restrict__ h0in, char* __restrict__ ws) {
  const int layer = blockIdx.x;
  const int tid = threadIdx.x;
  const float* src = h0in + layer * 16384;
  char* ring = ws + (layer ? 196608 : 65536) + 65536;  // slot 1, packed
  v2u* pubs = (v2u*)(ws + (layer ? 640 : 128)) + 32;   // slot 1
  for (int d = tid; d < 4096; d += 256) {              // d = packed f4 index
    int lb = d >> 7, b = (d >> 3) & 15, cq = (d & 7) << 2;
    v4f v = *(const v4f*)(src + (b << 10) + (lb << 5) + cq);
    cstore16(ring + ((size_t)d << 4), v);
  }
  __shared__ float red[256];
  const int lb = tid >> 3, su = tid & 7;
  float m = 0.0f;
  for (int b = su * 2; b < su * 2 + 2; ++b)
    for (int q = 0; q < 32; ++q) m = fmaxf(m, fabsf(src[b * 1024 + lb * 32 + q]));
  red[tid] = m;
  __syncthreads();
  if (su == 0) {
    float mm = red[tid];
#pragma unroll
    for (int i = 1; i < 8; ++i) mm = fmaxf(mm, red[tid + i]);
    v2u p;
    p.x = 0u;
    p.y = __float_as_uint(mm);
    cstore8((char*)&pubs[lb], p);
  }
}

// ---------------------------------------------------------------------------
__global__ void wabsmax_kernel(const float* __restrict__ w0, const float* __restrict__ w1,
                               const float* __restrict__ w2, const float* __restrict__ w3,
                               unsigned* wmax) {
  const int tensor = blockIdx.x >> 8;
  const int blk = blockIdx.x & 255;
  const float* w = tensor == 0 ? w0 : tensor == 1 ? w1 : tensor == 2 ? w2 : w3;
  const int tid = threadIdx.x;
  const float4* src = (const float4*)w;
  float m = 0.0f;
#pragma unroll
  for (int i = 0; i < 16; ++i) {
    float4 v = src[blk * 4096 + (i << 8) + tid];
    m = fmaxf(m, fmaxf(fmaxf(fabsf(v.x), fabsf(v.y)), fmaxf(fabsf(v.z), fabsf(v.w))));
  }
  __shared__ float red[256];
  red[tid] = m;
  __syncthreads();
  for (int off = 128; off > 0; off >>= 1) {
    if (tid < off) red[tid] = fmaxf(red[tid], red[tid + off]);
    __syncthreads();
  }
  if (tid == 0)
    __hip_atomic_fetch_max(&wmax[tensor], __float_as_uint(red[0]),
                           __ATOMIC_RELAXED, __HIP_MEMORY_SCOPE_AGENT);
}

// ---------------------------------------------------------------------------
__global__ void wquant_kernel(const float* __restrict__ w0, const float* __restrict__ w1,
                              const float* __restrict__ w2, const float* __restrict__ w3,
                              const unsigned* __restrict__ wmax,
                              unsigned char* __restrict__ wq) {
  const int tensor = blockIdx.x >> 12;
  const int blk = blockIdx.x & 4095;
  const float* w = tensor == 0 ? w0 : tensor == 1 ? w1 : tensor == 2 ? w2 : w3;
  const float s = fmaxf(__uint_as_float(wmax[tensor]), 1e-8f) / 127.0f;
  const int f4 = (blk << 8) + threadIdx.x;
  float4 v = ((const float4*)w)[f4];
  unsigned* dst = (unsigned*)(wq + (size_t)tensor * 4194304u);
  dst[f4] = pack4i(qdiv(v.x, s), qdiv(v.y, s), qdiv(v.z, s), qdiv(v.w, s));
}

// ---------------------------------------------------------------------------
// xq written SWIZZLED: xq_sw[t][kk][lane][j] = q(x[t][lane&15][kk*64+(lane>>4)*16+j])
__global__ void xquant_kernel(const float* __restrict__ x, float* __restrict__ xscale,
                              unsigned char* __restrict__ xq) {
  const int t = blockIdx.x;
  const int tid = threadIdx.x;
  const float4* src = (const float4*)(x + (size_t)t * 16384u);
  float4 vb[16];
  float m = 0.0f;
#pragma unroll
  for (int i = 0; i < 16; ++i) {
    float4 v = src[(i << 8) + tid];
    vb[i] = v;
    m = fmaxf(m, fmaxf(fmaxf(fabsf(v.x), fabsf(v.y)), fmaxf(fabsf(v.z), fabsf(v.w))));
  }
  __shared__ float red[256];
  red[tid] = m;
  __syncthreads();
  for (int off = 128; off > 0; off >>= 1) {
    if (tid < off) red[tid] = fmaxf(red[tid], red[tid + off]);
    __syncthreads();
  }
  __shared__ float ssh;
  if (tid == 0) {
    float s = fmaxf(red[0], 1e-8f) / 127.0f;
    xscale[t] = s;
    ssh = s;
  }
  __syncthreads();
  const float s = ssh;
  unsigned char* dst = xq + ((size_t)t << 14);
  const int kk = tid >> 4;              // k0 = 4*tid
  const int hi = (tid >> 2) & 3;
  const int jo = (tid & 3) << 2;
#pragma unroll
  for (int i = 0; i < 16; ++i) {        // i = batch
    float4 v = vb[i];
    unsigned q = pack4i(qdiv(v.x, s), qdiv(v.y, s), qdiv(v.z, s), qdiv(v.w, s));
    *(unsigned*)(dst + (kk << 10) + ((i | (hi << 4)) << 4) + jo) = q;
  }
}

// ---------------------------------------------------------------------------
__global__ __launch_bounds__(512, 2) void seq_kernel(
    const unsigned char* __restrict__ xq, const float* __restrict__ xscale,
    const unsigned char* __restrict__ wq_base, const unsigned* __restrict__ wmax,
    const float* __restrict__ bih0, const float* __restrict__ bhh0,
    const float* __restrict__ bih1, const float* __restrict__ bhh1,
    char* __restrict__ ws, const float* __restrict__ c0in, float* __restrict__ dout) {
  const int blk = blockIdx.x;
  const int layer = blk >> 5;
  const int lb = blk & 31;
  const int j0 = lb << 5;
  const int tid = threadIdx.x;
  const int w = tid >> 6;
  const int lane = tid & 63;
  const int gate = (lane >> 2) & 3;
  const int unit_l = (w << 2) + (lane & 3);
  const int b0 = (lane >> 4) << 2;

  v2u* pubs0 = (v2u*)(ws + 128);
  v2u* pubs1 = (v2u*)(ws + 640);
  float* hmax0f = (float*)(ws + 4096);
  char* h0f = ws + 65536;       // packed f32 ring [2][32][16][32]
  char* h1f = ws + 196608;
  char* h0qp = ws + 327680;     // packed i8 ring [8][32][16][32]

  __shared__ __align__(16) unsigned char ahq[16][1040];
  __shared__ __align__(16) unsigned char axq[16][1040];
  __shared__ float hstash[16][33];
  __shared__ float redw[8];

  const unsigned char* wqi = wq_base + (size_t)(2 * layer) * 4194304u;
  const unsigned char* wqh = wq_base + (size_t)(2 * layer + 1) * 4194304u;
  const float s_wi = fmaxf(__uint_as_float(wmax[2 * layer + 0]), 1e-8f) / 127.0f;
  const float s_wh = fmaxf(__uint_as_float(wmax[2 * layer + 1]), 1e-8f) / 127.0f;

  // MFMA 16x16x64 i8: A row=lane&15, k=(lane>>4)*16+j; D col=lane&15, row=(lane>>4)*4+r
  const int ncol = (gate << 10) + j0 + unit_l;
  const int ksub = (lane >> 4) << 4;
  const int arow = lane & 15;
  const int gbase = lane & ~12;

  v4i wfi[16], wfh[16];
  {
    const unsigned char* pi = wqi + (size_t)ncol * 1024u + ksub;
    const unsigned char* ph = wqh + (size_t)ncol * 1024u + ksub;
#pragma unroll
    for (int kk = 0; kk < 16; ++kk) {
      wfi[kk] = *(const v4i*)(pi + (kk << 6));
      wfh[kk] = *(const v4i*)(ph + (kk << 6));
    }
  }
  const float bsum = (layer ? bih1 : bih0)[ncol] + (layer ? bhh1 : bhh0)[ncol];

  float cr[4];
#pragma unroll
  for (int r = 0; r < 4; ++r) cr[r] = c0in[(layer << 14) + ((b0 + r) << 10) + j0 + unit_l];

  float bm = 0.f;

  if (layer == 0) {
    // ========================= LAYER 0: s = 0..T ==========================
    for (int s = 0; s <= T_STEPS; ++s) {
      const bool full = (s < T_STEPS);
      v4i ax0 = {0, 0, 0, 0}, ax1 = {0, 0, 0, 0};
      float sxs = 0.f;
      if (full) {  // pre-poll x work: swizzled coalesced loads -> fragments
        sxs = xscale[s];
        const unsigned char* xb = xq + ((size_t)s << 14) + (lane << 4);
        v4i xa[8];
#pragma unroll
        for (int kk = 0; kk < 8; ++kk) xa[kk] = *(const v4i*)(xb + (kk << 10));
#pragma unroll
        for (int kk = 0; kk < 8; kk += 2) {
          ax0 = MFMA_I8(xa[kk], wfi[kk], ax0, 0, 0, 0);
          ax1 = MFMA_I8(xa[kk + 1], wfi[kk + 1], ax1, 0, 0, 0);
        }
#pragma unroll
        for (int kk = 0; kk < 8; ++kk) xa[kk] = *(const v4i*)(xb + ((kk + 8) << 10));
#pragma unroll
        for (int kk = 0; kk < 8; kk += 2) {
          ax0 = MFMA_I8(xa[kk], wfi[kk + 8], ax0, 0, 0, 0);
          ax1 = MFMA_I8(xa[kk + 1], wfi[kk + 9], ax1, 0, 0, 0);
        }
      }
      // ---- poll (uniform slot): lanes<32 own pubs, lanes>=32 h0q ring guard
      const int slot = (s + 1) & 1;
      const v2u* pp = (lane < 32) ? (pubs0 + (slot << 5) + lane)
                                  : (pubs1 + (slot << 5) + (lane - 32));
      const unsigned tgt = (lane < 32) ? (unsigned)s
                                       : ((s >= 9) ? (unsigned)(s - 8) : 0u);
      v2u pv;
      unsigned guard = 0;
      for (;;) {
        pv = cload8w(pp);
        if (__ballot(pv.x >= tgt) == ~0ull) break;
        __builtin_amdgcn_s_sleep(1);
        if (++guard > (1u << 20)) break;
      }
      // ---- issue h-ring loads IMMEDIATELY (critical path) ----
      const char* hsrc = h0f + (size_t)slot * 65536;
      v4f hv[8];
#pragma unroll
      for (int i = 0; i < 8; ++i) hv[i] = cloadf(hsrc + (i << 13) + (tid << 4));
      // reduce block-maxes (overlaps load latency)
      float pm = __uint_as_float(pv.y);
#pragma unroll
      for (int m = 1; m < 32; m <<= 1) pm = fmaxf(pm, __shfl_xor(pm, m));
      const float gmax = __shfl(pm, 0);  // absmax of h0(s-1)
      const float sh = fmaxf(gmax, 1e-8f) / 127.0f;
      const float inv = 1.0f / sh;
      vdone();  // loads only (no stores outstanding)
      // quantize + stage to LDS (packed decode)
#pragma unroll
      for (int i = 0; i < 8; ++i) {
        unsigned uq = pack4i(qmul(hv[i].x, inv), qmul(hv[i].y, inv),
                             qmul(hv[i].z, inv), qmul(hv[i].w, inv));
        int o = (i << 13) + (tid << 4);
        int lbs = o >> 11, b = (o >> 7) & 15, c = (o & 127) >> 2;
        *(unsigned*)&ahq[b][(lbs << 5) + c] = uq;
      }
      __syncthreads();
      // publish h0q(s-1) from ahq bytes + hmax0f (off critical path)
      if (s > 0) {
        if (tid < 128) {
          int b = tid >> 3, c = (tid & 7) << 2;
          unsigned uq = *(const unsigned*)&ahq[b][j0 + c];
          cstore4u(h0qp + (size_t)((s - 1) & 7) * 16384 + (lb << 9) + (b << 5) + c, uq);
        }
        if (lb == 0 && tid == 256) cstore4f(&hmax0f[s - 1], gmax);
      }
      if (full) {
        v4i ah0 = {0, 0, 0, 0}, ah1 = {0, 0, 0, 0};
#pragma unroll
        for (int kk = 0; kk < 16; kk += 2) {
          v4i a = *(const v4i*)&ahq[arow][(kk << 6) + ksub];
          v4i b = *(const v4i*)&ahq[arow][((kk + 1) << 6) + ksub];
          ah0 = MFMA_I8(a, wfh[kk], ah0, 0, 0, 0);
          ah1 = MFMA_I8(b, wfh[kk + 1], ah1, 0, 0, 0);
        }
        const float fx = sxs * s_wi, fh = sh * s_wh;
        float am = 0.f;
#pragma unroll
        for (int r = 0; r < 4; ++r) {
          float gv = (float)(ax0[r] + ax1[r]) * fx + (float)(ah0[r] + ah1[r]) * fh + bsum;
          float xxv = (gate == 2) ? 2.f * gv : gv;
          float sg = __fdividef(1.f, 1.f + __expf(-xxv));
          float act = (gate == 2) ? 2.f * sg - 1.f : sg;
          float gi = __shfl(act, gbase);
          float gf = __shfl(act, gbase | 4);
          float gg = __shfl(act, gbase | 8);
          float go = __shfl(act, gbase | 12);
          float cn = gf * cr[r] + gi * gg;
          cr[r] = cn;
          float h = go * (2.f * __fdividef(1.f, 1.f + __expf(-2.f * cn)) - 1.f);
          if (gate == 0) hstash[b0 + r][unit_l] = h;
          am = fmaxf(am, fabsf(h));
        }
#pragma unroll
        for (int m = 1; m < 64; m <<= 1) am = fmaxf(am, __shfl_xor(am, m));
        if (lane == 0) redw[w] = am;
        __syncthreads();
        if (tid < 128) {  // packed coherent ring store (full lines)
          int b = tid >> 3, c = (tid & 7) << 2;
          v4f hw = {hstash[b][c], hstash[b][c + 1], hstash[b][c + 2], hstash[b][c + 3]};
          cstore16(h0f + (size_t)(s & 1) * 65536 + (lb << 11) + (b << 7) + (c << 2), hw);
          if (s == T_STEPS - 1)
            *(v4f*)(dout + 16777216u + (b << 10) + j0 + c) = hw;
        }
        if (tid == 0) {
          bm = redw[0];
#pragma unroll
          for (int i = 1; i < 8; ++i) bm = fmaxf(bm, redw[i]);
        }
      }
      vdone();
      __syncthreads();
      if (tid == 0) {
        v2u pub;
        pub.x = (unsigned)(s + 1);
        pub.y = __float_as_uint(bm);
        cstore8((char*)(pubs0 + ((s & 1) << 5) + lb), pub);
      }
    }
    if (gate == 0) {
#pragma unroll
      for (int r = 0; r < 4; ++r)
        dout[16777216u + 32768u + ((b0 + r) << 10) + j0 + unit_l] = cr[r];
    }
  } else {
    // ========================= LAYER 1: u = 0..T-1 ========================
    for (int u = 0; u < T_STEPS; ++u) {
      const int slot = (u + 1) & 1;
      const v2u* pp = (lane < 32) ? (pubs0 + (slot << 5) + lane)
                                  : (pubs1 + (slot << 5) + (lane - 32));
      const unsigned tgt = (lane < 32) ? (unsigned)(u + 2) : (unsigned)u;
      v2u pv;
      unsigned guard = 0;
      for (;;) {
        pv = cload8w(pp);
        if (__ballot(pv.x >= tgt) == ~0ull) break;
        __builtin_amdgcn_s_sleep(1);
        if (++guard > (1u << 20)) break;
      }
      // issue all loads: h0q(u) int8, h1 ring, sx scalar
      const char* qsrc = h0qp + (size_t)(u & 7) * 16384;
      v4i q0 = cloadi(qsrc + (tid << 4));
      v4i q1 = cloadi(qsrc + 8192 + (tid << 4));
      const char* hsrc = h1f + (size_t)slot * 65536;
      v4f hv[8];
#pragma unroll
      for (int i = 0; i < 8; ++i) hv[i] = cloadf(hsrc + (i << 13) + (tid << 4));
      unsigned sxb = cload4(&hmax0f[u]);
      // reduce own-layer maxes (lanes>=32 half)
      float pm = __uint_as_float(pv.y);
#pragma unroll
      for (int m = 1; m < 32; m <<= 1) pm = fmaxf(pm, __shfl_xor(pm, m));
      const float gmax1 = __shfl(pm, 32);  // absmax of h1(u-1)
      const float sh = fmaxf(gmax1, 1e-8f) / 127.0f;
      const float inv = 1.0f / sh;
      vdone();
      const float sxs = fmaxf(__uint_as_float(sxb), 1e-8f) / 127.0f;
      // stage x-side int8 (packed decode)
      {
        int o = tid << 4;
        *(v4i*)&axq[(o >> 5) & 15][((o >> 9) << 5) + (o & 31)] = q0;
        int o1 = o + 8192;
        *(v4i*)&axq[(o1 >> 5) & 15][((o1 >> 9) << 5) + (o1 & 31)] = q1;
      }
      // quantize + stage h-side
#pragma unroll
      for (int i = 0; i < 8; ++i) {
        unsigned uq = pack4i(qmul(hv[i].x, inv), qmul(hv[i].y, inv),
                             qmul(hv[i].z, inv), qmul(hv[i].w, inv));
        int o = (i << 13) + (tid << 4);
        int lbs = o >> 11, b = (o >> 7) & 15, c = (o & 127) >> 2;
        *(unsigned*)&ahq[b][(lbs << 5) + c] = uq;
      }
      __syncthreads();
      v4i ax0 = {0, 0, 0, 0}, ax1 = {0, 0, 0, 0};
      v4i ah0 = {0, 0, 0, 0}, ah1 = {0, 0, 0, 0};
#pragma unroll
      for (int kk = 0; kk < 16; kk += 2) {
        v4i a0 = *(const v4i*)&axq[arow][(kk << 6) + ksub];
        v4i a1 = *(const v4i*)&axq[arow][((kk + 1) << 6) + ksub];
        v4i b0v = *(const v4i*)&ahq[arow][(kk << 6) + ksub];
        v4i b1v = *(const v4i*)&ahq[arow][((kk + 1) << 6) + ksub];
        ax0 = MFMA_I8(a0, wfi[kk], ax0, 0, 0, 0);
        ax1 = MFMA_I8(a1, wfi[kk + 1], ax1, 0, 0, 0);
        ah0 = MFMA_I8(b0v, wfh[kk], ah0, 0, 0, 0);
        ah1 = MFMA_I8(b1v, wfh[kk + 1], ah1, 0, 0, 0);
      }
      const float fx = sxs * s_wi, fh = sh * s_wh;
      float am = 0.f;
#pragma unroll
      for (int r = 0; r < 4; ++r) {
        float gv = (float)(ax0[r] + ax1[r]) * fx + (float)(ah0[r] + ah1[r]) * fh + bsum;
        float xxv = (gate == 2) ? 2.f * gv : gv;
        float sg = __fdividef(1.f, 1.f + __expf(-xxv));
        float act = (gate == 2) ? 2.f * sg - 1.f : sg;
        float gi = __shfl(act, gbase);
        float gf = __shfl(act, gbase | 4);
        float gg = __shfl(act, gbase | 8);
        float go = __shfl(act, gbase | 12);
        float cn = gf * cr[r] + gi * gg;
        cr[r] = cn;
        float h = go * (2.f * __fdividef(1.f, 1.f + __expf(-2.f * cn)) - 1.f);
        if (gate == 0) hstash[b0 + r][unit_l] = h;
        am = fmaxf(am, fabsf(h));
      }
#pragma unroll
      for (int m = 1; m < 64; m <<= 1) am = fmaxf(am, __shfl_xor(am, m));
      if (lane == 0) redw[w] = am;
      __syncthreads();
      if (tid < 128) {
        int b = tid >> 3, c = (tid & 7) << 2;
        v4f hw = {hstash[b][c], hstash[b][c + 1], hstash[b][c + 2], hstash[b][c + 3]};
        cstore16(h1f + (size_t)(u & 1) * 65536 + (lb << 11) + (b << 7) + (c << 2), hw);
        *(v4f*)(dout + ((size_t)u << 14) + (b << 10) + j0 + c) = hw;  // y (plain)
        if (u == T_STEPS - 1)
          *(v4f*)(dout + 16777216u + 16384u + (b << 10) + j0 + c) = hw;
      }
      if (tid == 0) {
        bm = redw[0];
#pragma unroll
        for (int i = 1; i < 8; ++i) bm = fmaxf(bm, redw[i]);
      }
      vdone();
      __syncthreads();
      if (tid == 0) {
        v2u pub;
        pub.x = (unsigned)(u + 1);
        pub.y = __float_as_uint(bm);
        cstore8((char*)(pubs1 + ((u & 1) << 5) + lb), pub);
      }
    }
    if (gate == 0) {
#pragma unroll
      for (int r = 0; r < 4; ++r)
        dout[16777216u + 32768u + 16384u + ((b0 + r) << 10) + j0 + unit_l] = cr[r];
    }
  }
}

// ---------------------------------------------------------------------------
extern "C" void kernel_launch(void* const* d_in, const int* in_sizes, int n_in,
                              void* d_out, int out_size, void* d_ws, size_t ws_size,
                              hipStream_t stream) {
  (void)in_sizes; (void)n_in; (void)out_size; (void)ws_size;
  const float* x     = (const float*)d_in[0];
  const float* h0in  = (const float*)d_in[1];
  const float* c0in  = (const float*)d_in[2];
  const float* w_ih0 = (const float*)d_in[3];
  const float* w_hh0 = (const float*)d_in[4];
  const float* b_ih0 = (const float*)d_in[5];
  const float* b_hh0 = (const float*)d_in[6];
  const float* w_ih1 = (const float*)d_in[7];
  const float* w_hh1 = (const float*)d_in[8];
  const float* b_ih1 = (const float*)d_in[9];
  const float* b_hh1 = (const float*)d_in[10];

  char* ws = (char*)d_ws;
  unsigned* wmax   = (unsigned*)(ws + 0);
  float* xscale    = (float*)(ws + 8192);
  unsigned char* wqb = (unsigned char*)(ws + (1u << 20));
  unsigned char* xq  = (unsigned char*)(ws + (1u << 20) + 4u * 4194304u);

  hipMemsetAsync(ws, 0, 65536, stream);  // wmax, pubs, hmax0f, xscale
  hipLaunchKernelGGL(init_kernel, dim3(2), dim3(256), 0, stream, h0in, ws);
  hipLaunchKernelGGL(wabsmax_kernel, dim3(1024), dim3(256), 0, stream,
                     w_ih0, w_hh0, w_ih1, w_hh1, wmax);
  hipLaunchKernelGGL(wquant_kernel, dim3(16384), dim3(256), 0, stream,
                     w_ih0, w_hh0, w_ih1, w_hh1, wmax, wqb);
  hipLaunchKernelGGL(xquant_kernel, dim3(1024), dim3(256), 0, stream,
                     x, xscale, xq);
  hipLaunchKernelGGL(seq_kernel, dim3(64), dim3(512), 0, stream,
                     xq, xscale, wqb, wmax,
                     b_ih0, b_hh0, b_ih1, b_hh1,
                     ws, c0in, (float*)d_out);
}